// Round 4
// baseline (271.831 us; speedup 1.0000x reference)
//
#include <hip/hip_runtime.h>
#include <hip/hip_bf16.h>
#include <stdint.h>

// MPNN latency predictor, MI355X — round 11.
// vs R10: k_msg_fused's real floor identified as L2 STREAMING of w2tf:
// every 64-edge block streamed the whole 528KB tensor -> 512 x 528KB =
// 270MB of L2 reads per dispatch (FETCH_SIZE ~6MB proves they're L2 hits,
// so the cost is invisible in hbm counters but real in time).
// R11 halves the stream: 256 blocks x 512 threads (8 waves = 2 edge-halves
// x 4 kk-groups). Each kk-group's staged buffer is SHARED by its two
// edge-half waves (double-buffered, 64KB). Sync uses raw s_barrier +
// hand-counted vmcnt(4) (NOT __syncthreads in the loop: its implicit
// vmcnt(0) drain would serialize staging). Reduce reuses the stage region
// in 4 nf-rounds. All other kernels unchanged from R10.

#define N_NODES 32768
#define N_EDGES 32768
#define STEPS 3

typedef __attribute__((ext_vector_type(8))) short short8;   // 8 bf16 = 4 VGPRs
typedef __attribute__((ext_vector_type(4))) float float4v;  // MFMA C/D

__device__ __forceinline__ float bf2f(unsigned short u) {
    union { unsigned int i; float f; } v; v.i = ((unsigned int)u) << 16; return v.f;
}
__device__ __forceinline__ unsigned short f2bf(float f) {  // RNE
    union { float f; unsigned int i; } v; v.f = f;
    unsigned int x = v.i;
    return (unsigned short)((x + 0x7fffu + ((x >> 16) & 1u)) >> 16);
}

// async global->LDS, 16B/lane; lds dest = wave-uniform base + lane*16
__device__ __forceinline__ void gload_lds16(const void* g, void* l) {
    __builtin_amdgcn_global_load_lds(
        (__attribute__((address_space(1))) void*)g,
        (__attribute__((address_space(3))) void*)l, 16, 0, 0);
}

// ===================== fused setup kernel ==================================
// blockIdx segments:
//  [0,144)       rootTf (4096) + wcombf (32768)      — frag-interleaved
//  [144,1184)    w2tf (266240 valid + 4096 pad)       — frag-interleaved
//  [1184,1232)   wd1f (10240) + wd2f (2048)           — frag-interleaved
//  [1232,9424)   proj: hb = bf16(tanh([x,u]@Wp^T+bp))
//  [9424,17616)  edge hidden TRANSPOSED: hidT[j][e] = relu(ea@We1^T+be1)
//  [17616,17648) zero cnts (32768 floats)
__global__ __launch_bounds__(256) void k_setup(
    const float* __restrict__ root, const float* __restrict__ Wih,
    const float* __restrict__ Whh,
    const float* __restrict__ We2, const float* __restrict__ be2,
    const float* __restrict__ Wd1, const float* __restrict__ bd1,
    const float* __restrict__ Wd2,
    const float* __restrict__ x, const float* __restrict__ u,
    const float* __restrict__ Wp, const float* __restrict__ bp,
    const float* __restrict__ ea, const float* __restrict__ We1,
    const float* __restrict__ be1,
    unsigned short* __restrict__ rootTf, unsigned short* __restrict__ wcombf,
    unsigned short* __restrict__ w2tf,
    unsigned short* __restrict__ wd1f, unsigned short* __restrict__ wd2f,
    unsigned short* __restrict__ hb,
    unsigned short* __restrict__ hidT, float* __restrict__ cnts)
{
    int b = blockIdx.x, tid = threadIdx.x;
    if (b < 144) {
        int i = b * 256 + tid;
        if (i < 4096) {
            int j = i & 7, lane = (i >> 3) & 63, g = i >> 9;   // g<8
            int kb = g >> 2, nf = g & 3;
            int o = nf * 16 + (lane & 15);
            int k = kb * 32 + (lane >> 4) * 8 + j;
            rootTf[i] = f2bf(root[k * 64 + o]);
        } else if (i < 4096 + 32768) {
            int t = i - 4096;
            int j = t & 7, lane = (t >> 3) & 63, g = t >> 9;   // g<64
            int kb = g >> 4, nf = g & 15;
            int cp = nf * 16 + (lane & 15);
            int k = kb * 32 + (lane >> 4) * 8 + j;
            float v;
            if (cp < 128)      v = (k < 64) ? Wih[cp * 64 + k] : Whh[cp * 64 + (k - 64)];
            else if (cp < 192) v = (k < 64) ? Wih[cp * 64 + k] : 0.f;
            else               v = (k < 64) ? 0.f : Whh[(cp - 64) * 64 + (k - 64)];
            wcombf[t] = f2bf(v);
        }
    } else if (b < 1184) {
        int t = (b - 144) * 256 + tid;   // t < 266240
        if (t < 65 * 4096) {
            int kk = t >> 12, r = t & 4095;
            int j = r & 7, lane = (r >> 3) & 63, g = r >> 9;  // g<8
            int half = g >> 2, nf = g & 3;
            int o = nf * 16 + (lane & 15);
            int hh = half * 32 + (lane >> 4) * 8 + j;
            float v = (kk < 64) ? We2[((size_t)(hh * 64 + o)) * 64 + kk]
                                : be2[(size_t)hh * 64 + o];
            w2tf[t] = f2bf(v);
        }
    } else if (b < 1232) {
        int i = (b - 1184) * 256 + tid;
        if (i < 10240) {
            int j = i & 7, lane = (i >> 3) & 63, g = i >> 9;  // g<20
            int kb = g >> 2, nf = g & 3;
            int o = nf * 16 + (lane & 15);
            int k = kb * 32 + (lane >> 4) * 8 + j;
            float v = (k < 133) ? Wd1[(size_t)o * 133 + k] : (k == 133 ? bd1[o] : 0.f);
            wd1f[i] = f2bf(v);
        } else if (i < 10240 + 2048) {
            int t = i - 10240;
            int j = t & 7, lane = (t >> 3) & 63, g = t >> 9;  // g<4
            int kb = g >> 1, nf = g & 1;
            int o = nf * 16 + (lane & 15);
            int k = kb * 32 + (lane >> 4) * 8 + j;
            wd2f[t] = f2bf(Wd2[(size_t)o * 64 + k]);
        }
    } else if (b < 9424) {
        int idx = (b - 1232) * 256 + tid;
        int n = idx >> 6, j = idx & 63;
        const float* wr = Wp + j * 23;
        const float* xr = x + (size_t)n * 12;
        float s = bp[j];
#pragma unroll
        for (int i = 0; i < 12; i++) s += xr[i] * wr[i];
#pragma unroll
        for (int i = 0; i < 11; i++) s += u[i] * wr[12 + i];
        hb[idx] = f2bf(tanhf(s));
    } else if (b < 17616) {
        int idx = (b - 9424) * 256 + tid;           // idx < 2^21
        int el = idx & 63, j = (idx >> 6) & 63, eb = idx >> 12;
        int e = eb * 64 + el;                       // lane-varying e -> coalesced
        float s = be1[j];
#pragma unroll
        for (int i = 0; i < 5; i++) s += ea[(size_t)e * 5 + i] * We1[j * 5 + i];
        hidT[(size_t)j * N_EDGES + e] = f2bf(s > 0.f ? s : 0.f);
    } else {
        int idx = (b - 17616) * 1024 + tid * 4;
        if (idx < 32768) {
            float4v z = {0.f, 0.f, 0.f, 0.f};
            *(float4v*)(cnts + idx) = z;
        }
    }
}

__global__ __launch_bounds__(256) void k_counts(
    const int* __restrict__ ei, float* __restrict__ counts)
{
    int i = blockIdx.x * 256 + threadIdx.x;
    if (i < N_EDGES) atomicAdd(&counts[ei[N_EDGES + i]], 1.0f);
}

// one-time exclusive prefix sum of counts -> off[0..N], plus working copy woff
__global__ __launch_bounds__(1024) void k_scan(
    const float* __restrict__ cnts, int* __restrict__ off, int* __restrict__ woff)
{
    __shared__ int part[1024];
    int t = threadIdx.x;
    int loc[32];
    int s = 0;
#pragma unroll
    for (int i = 0; i < 32; i++) { loc[i] = s; s += (int)cnts[t * 32 + i]; }
    part[t] = s;
    __syncthreads();
    for (int d = 1; d < 1024; d <<= 1) {
        int y = (t >= d) ? part[t - d] : 0;
        __syncthreads();
        part[t] += y;
        __syncthreads();
    }
    int pre = (t == 0) ? 0 : part[t - 1];
#pragma unroll
    for (int i = 0; i < 32; i++) {
        off[t * 32 + i] = pre + loc[i];
        woff[t * 32 + i] = pre + loc[i];
    }
    if (t == 1023) off[32768] = part[1023];
}

// one-time: place edge ids into dst-sorted slots (32K atomics, once)
__global__ __launch_bounds__(256) void k_scatter(
    const int* __restrict__ ei, int* __restrict__ woff, int* __restrict__ eorder)
{
    int e = blockIdx.x * 256 + threadIdx.x;
    if (e < N_EDGES) {
        int d = ei[N_EDGES + e];
        int slot = atomicAdd(&woff[d], 1);
        eorder[slot] = e;
    }
}

// ===================== fused msg GEMM ======================================
// 512 threads = 8 waves: wave = eg*4 + kg. eg in {0,1} owns a 64-edge half
// (4 M-tiles); kg in {0..3} owns kk-slice kg*16..+15 (kg=3 also kk=64 bias).
// The two eg-waves of a kg SHARE one double-buffered staged kk-buffer
// (stage: 4 kg x 2 db x 8KB = 64KB) -> per-block w2tf stream is 528KB for
// 128 edges (half of R10's per-edge cost). Loop sync: raw s_barrier +
// counted vmcnt(4) per wave; NO __syncthreads (would vmcnt(0)-drain).
// 256 blocks, 1/CU. Reduce over kg partials in 4 nf-rounds reusing stage.
__global__ __launch_bounds__(512, 2) void k_msg_fused(
    const unsigned short* __restrict__ hidT,  // (64, E) bf16
    const unsigned short* __restrict__ hb,    // (N,64) bf16
    const unsigned short* __restrict__ w2tf,  // (66*4096) frag-interleaved
    const int* __restrict__ ei,
    float* __restrict__ msgbuf)               // (E,64) f32 dense
{
    // LDS: [0,65536)      stage: kg x db x 4096 ushort
    //      [65536,81920)  hvl: 64 kk x 128 e bf16
    //      reduce overlay on stage: red[4 kg][128 row][18] f32 = 36864B
    __shared__ __attribute__((aligned(16))) unsigned char smem[81920];
    unsigned short* stg = (unsigned short*)smem;
    unsigned short* hvl = (unsigned short*)(smem + 65536);
    float* red = (float*)smem;

    int tid = threadIdx.x, w = tid >> 6, lane = tid & 63;
    int l15 = lane & 15, quad = lane >> 4;
    int kg = w & 3, eg = w >> 2;
    int ebase = blockIdx.x * 128;
    int n_w = 16 + (kg == 3 ? 1 : 0);   // kg3 takes the bias row kk=64

    // ---- preamble: hvl[64 kk][128 e] cooperative load (8 rows/wave) ----
#pragma unroll
    for (int i = 0; i < 8; i++) {
        int row = w * 8 + i;
        unsigned int v = *((const unsigned int*)(hidT + (size_t)row * N_EDGES + ebase) + lane);
        *((unsigned int*)hvl + row * 64 + lane) = v;
    }
    // ---- static A-frags: this eg-half's 4 edge-tiles x 2 K-halves ----
    short8 afr[4][2];
#pragma unroll
    for (int t = 0; t < 4; t++) {
        int src = ei[ebase + eg * 64 + t * 16 + l15];
#pragma unroll
        for (int hh = 0; hh < 2; hh++)
            afr[t][hh] = *(const short8*)(hb + (size_t)src * 64 + hh * 32 + quad * 8);
    }

    // stage kk-row (kg*16+r) into stage[kg][db]; each eg-wave stages its 4KB
    auto stage = [&](int r, int db) {
        const unsigned short* g = w2tf + (size_t)(kg * 16 + r) * 4096;
        unsigned short* d = stg + (kg * 2 + db) * 4096;
#pragma unroll
        for (int c = 0; c < 4; c++) {
            int ch = eg * 4 + c;
            gload_lds16(g + ch * 512 + lane * 8, d + ch * 512);
        }
    };

    stage(0, 0);
    stage(1, 1);
    asm volatile("s_waitcnt lgkmcnt(0)" ::: "memory");  // hvl writes done
    __builtin_amdgcn_s_barrier();                       // hvl visible to all

    float4v acc[4][4] = {};   // [tile][nf]
    for (int r = 0; r <= 16; r++) {
        int db = r & 1;
        // wait for stage r (my 4 loads; stage r+1's 4 may stay in flight)
        if (r >= n_w - 1) { asm volatile("s_waitcnt vmcnt(0)" ::: "memory"); }
        else              { asm volatile("s_waitcnt vmcnt(4)" ::: "memory"); }
        __builtin_amdgcn_s_barrier();   // both eg-waves' halves of stage r landed

        bool act = (r < n_w);
        short8 bfr[2][4];
        unsigned long long hu[4] = {0ull, 0ull, 0ull, 0ull};
        bool bias = (r == 16);
        if (act) {
            const unsigned short* bb = stg + (kg * 2 + db) * 4096;
#pragma unroll
            for (int hh = 0; hh < 2; hh++)
#pragma unroll
                for (int nf = 0; nf < 4; nf++)
                    bfr[hh][nf] = *(const short8*)(bb + (hh * 4 + nf) * 512 + lane * 8);
            if (!bias) {
#pragma unroll
                for (int t = 0; t < 4; t++)
                    hu[t] = *(const unsigned long long*)(hvl + (kg * 16 + r) * 128 + eg * 64 + t * 16 + quad * 4);
            }
        }
        asm volatile("s_waitcnt lgkmcnt(0)" ::: "memory");  // my LDS reads done
        __builtin_amdgcn_s_barrier();   // everyone's reads done -> db reusable
        if (r + 2 < n_w) stage(r + 2, db);

        if (act) {
#pragma unroll
            for (int t = 0; t < 4; t++) {
                float4v T[4];
#pragma unroll
                for (int nf = 0; nf < 4; nf++) {
                    float4v z = {0.f, 0.f, 0.f, 0.f};
                    T[nf] = __builtin_amdgcn_mfma_f32_16x16x32_bf16(afr[t][0], bfr[0][nf], z, 0, 0, 0);
                }
#pragma unroll
                for (int nf = 0; nf < 4; nf++)
                    T[nf] = __builtin_amdgcn_mfma_f32_16x16x32_bf16(afr[t][1], bfr[1][nf], T[nf], 0, 0, 0);
#pragma unroll
                for (int rr = 0; rr < 4; rr++) {
                    float hvv = bias ? 1.0f : bf2f((unsigned short)(hu[t] >> (16 * rr)));
#pragma unroll
                    for (int nf = 0; nf < 4; nf++)
                        acc[t][nf][rr] += hvv * T[nf][rr];
                }
            }
        }
    }

    // ---- reduce kg partials in 4 nf-rounds (red overlays stage region) ----
    int row_w = tid >> 2, kq = tid & 3;        // 128 rows x 4 col-chunks
#pragma unroll
    for (int nf = 0; nf < 4; nf++) {
        __syncthreads();   // red region free (round 0: also closes main loop)
#pragma unroll
        for (int t = 0; t < 4; t++)
#pragma unroll
            for (int rr = 0; rr < 4; rr++)
                red[kg * 2304 + (eg * 64 + t * 16 + quad * 4 + rr) * 18 + l15] = acc[t][nf][rr];
        __syncthreads();
        float4v s = {0.f, 0.f, 0.f, 0.f};
#pragma unroll
        for (int g2 = 0; g2 < 4; g2++) {
            const float* rp = red + g2 * 2304 + row_w * 18 + kq * 4;
#pragma unroll
            for (int j = 0; j < 4; j++) s[j] += rp[j];
        }
        *(float4v*)(msgbuf + (size_t)(ebase + row_w) * 64 + nf * 16 + kq * 4) = s;
    }
}

// ===================== fused node update ===================================
// Gathers msgbuf rows via dst-sorted edge list (no atomics, no agg buffer).
__global__ __launch_bounds__(256) void k_node(
    const unsigned short* __restrict__ hb_in,
    const unsigned short* __restrict__ rootTf,
    const unsigned short* __restrict__ wcombf,
    const float* __restrict__ msgbuf, const int* __restrict__ off,
    const int* __restrict__ eorder,
    const float* __restrict__ counts,
    const float* __restrict__ conv_b,
    const float* __restrict__ bih, const float* __restrict__ bhh,
    unsigned short* __restrict__ hb_out)
{
    __shared__ unsigned short m_lds[64 * 72];
    __shared__ float aggl[64 * 68];
    int tid = threadIdx.x, w = tid >> 6, lane = tid & 63;
    int l15 = lane & 15, quad = lane >> 4;
    int node0 = blockIdx.x * 64;
    int row0 = w * 16;

    // ---- gather-aggregate: 4 threads per node x 16 cols ----
    {
        int nl = tid >> 2, cg = tid & 3;
        int nn = node0 + nl;
        int s0 = off[nn], s1 = off[nn + 1];
        float acc[16] = {};
        for (int sl = s0; sl < s1; sl++) {
            int e = eorder[sl];
            const float* mr = msgbuf + (size_t)e * 64 + cg * 16;
#pragma unroll
            for (int q = 0; q < 4; q++) {
                float4v v = *(const float4v*)(mr + 4 * q);
#pragma unroll
                for (int j = 0; j < 4; j++) acc[4 * q + j] += v[j];
            }
        }
#pragma unroll
        for (int k = 0; k < 16; k++) aggl[nl * 68 + cg * 16 + k] = acc[k];
    }
    __syncthreads();

    float4v acc1[4] = {};
    {
        short8 a1[2];
#pragma unroll
        for (int kb = 0; kb < 2; kb++)
            a1[kb] = *(const short8*)(hb_in + (size_t)(node0 + row0 + l15) * 64 + kb * 32 + quad * 8);
#pragma unroll
        for (int kb = 0; kb < 2; kb++)
#pragma unroll
            for (int nf = 0; nf < 4; nf++) {
                short8 b = *(const short8*)(rootTf + (size_t)((kb * 4 + nf) * 64 + lane) * 8);
                acc1[nf] = __builtin_amdgcn_mfma_f32_16x16x32_bf16(a1[kb], b, acc1[nf], 0, 0, 0);
            }
    }
#pragma unroll
    for (int rr = 0; rr < 4; rr++) {
        int nl = row0 + quad * 4 + rr;
        float cnt = counts[node0 + nl]; if (cnt < 1.f) cnt = 1.f;
        float rcp = 1.f / cnt;
#pragma unroll
        for (int nf = 0; nf < 4; nf++) {
            int c = nf * 16 + l15;
            float av = aggl[nl * 68 + c];
            float mv = av * rcp + acc1[nf][rr] + conv_b[c];
            m_lds[nl * 72 + c] = f2bf(mv > 0.f ? mv : 0.f);
        }
    }
    __syncthreads();

    float4v acc2[16] = {};
#pragma unroll
    for (int kb = 0; kb < 4; kb++) {
        short8 a2;
        if (kb < 2)
            a2 = *(const short8*)(m_lds + (row0 + l15) * 72 + kb * 32 + quad * 8);
        else
            a2 = *(const short8*)(hb_in + (size_t)(node0 + row0 + l15) * 64 + (kb - 2) * 32 + quad * 8);
#pragma unroll
        for (int nf = 0; nf < 16; nf++) {
            short8 b = *(const short8*)(wcombf + (size_t)((kb * 16 + nf) * 64 + lane) * 8);
            acc2[nf] = __builtin_amdgcn_mfma_f32_16x16x32_bf16(a2, b, acc2[nf], 0, 0, 0);
        }
    }

#pragma unroll
    for (int nf0 = 0; nf0 < 4; nf0++) {
        int c = nf0 * 16 + l15;
        float br = bih[c] + bhh[c];
        float bz = bih[64 + c] + bhh[64 + c];
        float bni = bih[128 + c], bnh = bhh[128 + c];
#pragma unroll
        for (int rr = 0; rr < 4; rr++) {
            int node = node0 + row0 + quad * 4 + rr;
            float gr = 1.f / (1.f + __expf(-(acc2[nf0][rr] + br)));
            float gz = 1.f / (1.f + __expf(-(acc2[nf0 + 4][rr] + bz)));
            float ng = tanhf(acc2[nf0 + 8][rr] + bni + gr * (acc2[nf0 + 12][rr] + bnh));
            float ho = bf2f(hb_in[(size_t)node * 64 + c]);
            float hn = (1.f - gz) * ng + gz * ho;
            hb_out[(size_t)node * 64 + c] = f2bf(hn);
        }
    }
}

// ===================== MFMA decoder ========================================
__global__ __launch_bounds__(256) void k_decoder(
    const unsigned short* __restrict__ hb, const int* __restrict__ ei,
    const float* __restrict__ ea,
    const unsigned short* __restrict__ wd1f, const unsigned short* __restrict__ wd2f,
    const float* __restrict__ bd2,
    const float* __restrict__ Wd3, const float* __restrict__ bd3,
    float* __restrict__ out)
{
    __shared__ unsigned short d1f[4][1024];  // per-wave: 2 frags x 512
    __shared__ float d2s[4][16 * 33];        // per-wave: 16 edges x 32 (+pad)
    int tid = threadIdx.x, w = tid >> 6, lane = tid & 63;
    int l15 = lane & 15, quad = lane >> 4;
    int ebase = blockIdx.x * 64 + w * 16;
    int e = ebase + l15;
    int src = ei[e], dst = ei[N_EDGES + e];

    short8 a[5];
#pragma unroll
    for (int kb = 0; kb < 2; kb++) {
        a[kb]     = *(const short8*)(hb + (size_t)src * 64 + kb * 32 + quad * 8);
        a[2 + kb] = *(const short8*)(hb + (size_t)dst * 64 + kb * 32 + quad * 8);
    }
    {
        union { short8 v; unsigned short u[8]; } tea;
#pragma unroll
        for (int j = 0; j < 8; j++) {
            float vv = 0.f;
            if (quad == 0) vv = (j < 5) ? ea[(size_t)e * 5 + j] : (j == 5 ? 1.f : 0.f);
            tea.u[j] = f2bf(vv);
        }
        a[4] = tea.v;
    }

    float4v acc1[4] = {};
#pragma unroll
    for (int kb = 0; kb < 5; kb++)
#pragma unroll
        for (int nf = 0; nf < 4; nf++) {
            short8 b = *(const short8*)(wd1f + (size_t)((kb * 4 + nf) * 64 + lane) * 8);
            acc1[nf] = __builtin_amdgcn_mfma_f32_16x16x32_bf16(a[kb], b, acc1[nf], 0, 0, 0);
        }
#pragma unroll
    for (int nf = 0; nf < 4; nf++) {
        int kbp = nf >> 1;
        int lanep_hi = ((nf & 1) * 2 + (l15 >> 3)) * 16;
        int jp = l15 & 7;
#pragma unroll
        for (int r = 0; r < 4; r++) {
            float v = acc1[nf][r];
            d1f[w][kbp * 512 + (lanep_hi + quad * 4 + r) * 8 + jp] = f2bf(v > 0.f ? v : 0.f);
        }
    }
    float4v acc2[2] = {};
#pragma unroll
    for (int kb = 0; kb < 2; kb++) {
        short8 a2 = *(const short8*)(&d1f[w][kb * 512 + lane * 8]);
#pragma unroll
        for (int nf = 0; nf < 2; nf++) {
            short8 b = *(const short8*)(wd2f + (size_t)((kb * 2 + nf) * 64 + lane) * 8);
            acc2[nf] = __builtin_amdgcn_mfma_f32_16x16x32_bf16(a2, b, acc2[nf], 0, 0, 0);
        }
    }
#pragma unroll
    for (int nf = 0; nf < 2; nf++) {
        int c = nf * 16 + l15;
        float bias = bd2[c];
#pragma unroll
        for (int r = 0; r < 4; r++) {
            float v = acc2[nf][r] + bias;
            d2s[w][(quad * 4 + r) * 33 + c] = v > 0.f ? v : 0.f;
        }
    }
    {
        int e_l = lane >> 2, t = lane & 3;
        float s = bd3[t];
        const float* w3 = Wd3 + t * 32;
        const float* dr = &d2s[w][e_l * 33];
#pragma unroll
        for (int k = 0; k < 32; k++) s += w3[k] * dr[k];
        out[(size_t)(ebase + e_l) * 4 + t] = s;
    }
}

extern "C" void kernel_launch(void* const* d_in, const int* in_sizes, int n_in,
                              void* d_out, int out_size, void* d_ws, size_t ws_size,
                              hipStream_t stream)
{
    const float* x      = (const float*)d_in[0];
    const int*   ei     = (const int*)d_in[1];
    const float* ea     = (const float*)d_in[2];
    const float* u      = (const float*)d_in[3];
    const float* Wp     = (const float*)d_in[4];
    const float* bp     = (const float*)d_in[5];
    const float* We1    = (const float*)d_in[6];
    const float* be1    = (const float*)d_in[7];
    const float* We2    = (const float*)d_in[8];
    const float* be2    = (const float*)d_in[9];
    const float* root   = (const float*)d_in[10];
    const float* conv_b = (const float*)d_in[11];
    const float* Wih    = (const float*)d_in[12];
    const float* bih    = (const float*)d_in[13];
    const float* Whh    = (const float*)d_in[14];
    const float* bhh    = (const float*)d_in[15];
    const float* Wd1    = (const float*)d_in[16];
    const float* bd1    = (const float*)d_in[17];
    const float* Wd2    = (const float*)d_in[18];
    const float* bd2    = (const float*)d_in[19];
    const float* Wd3    = (const float*)d_in[20];
    const float* bd3    = (const float*)d_in[21];
    float* out = (float*)d_out;

    char* ws = (char*)d_ws;
    size_t off_b = 0;
    auto take = [&](size_t bytes) -> char* {
        char* p = ws + off_b; off_b = (off_b + bytes + 255) & ~(size_t)255; return p;
    };
    unsigned short* hb     = (unsigned short*)take((size_t)N_NODES * 64 * 2);
    unsigned short* hidT   = (unsigned short*)take((size_t)N_EDGES * 64 * 2);
    float*          msgbuf = (float*)take((size_t)N_EDGES * 64 * 4);
    float*          cnts   = (float*)take((size_t)N_NODES * 4);
    int*            off    = (int*)take((size_t)(N_NODES + 1) * 4);
    int*            woff   = (int*)take((size_t)N_NODES * 4);
    int*            eorder = (int*)take((size_t)N_EDGES * 4);
    unsigned short* w2tf   = (unsigned short*)take((size_t)66 * 4096 * 2);  // +1 pad blk
    unsigned short* rootTf = (unsigned short*)take((size_t)4096 * 2);
    unsigned short* wcombf = (unsigned short*)take((size_t)32768 * 2);
    unsigned short* wd1f   = (unsigned short*)take((size_t)10240 * 2);
    unsigned short* wd2f   = (unsigned short*)take((size_t)2048 * 2);
    (void)ws_size;

    k_setup<<<17648, 256, 0, stream>>>(root, Wih, Whh, We2, be2, Wd1, bd1, Wd2,
                                       x, u, Wp, bp, ea, We1, be1,
                                       rootTf, wcombf, w2tf, wd1f, wd2f,
                                       hb, hidT, cnts);
    k_counts<<<128, 256, 0, stream>>>(ei, cnts);
    k_scan<<<1, 1024, 0, stream>>>(cnts, off, woff);
    k_scatter<<<128, 256, 0, stream>>>(ei, woff, eorder);

    for (int s = 0; s < STEPS; s++) {
        k_msg_fused<<<N_EDGES / 128, 512, 0, stream>>>(hidT, hb, w2tf, ei, msgbuf);
        k_node<<<N_NODES / 64, 256, 0, stream>>>(hb, rootTf, wcombf, msgbuf, off,
                                                 eorder, cnts, conv_b, bih, bhh, hb);
    }
    k_decoder<<<N_EDGES / 64, 256, 0, stream>>>(hb, ei, ea, wd1f, wd2f, bd2,
                                                Wd3, bd3, out);
}

// Round 5
// 261.912 us; speedup vs baseline: 1.0379x; 1.0379x over previous
//
#include <hip/hip_runtime.h>
#include <hip/hip_bf16.h>
#include <stdint.h>

// MPNN latency predictor, MI355X — round 12.
// Evidence: R7/R9/R10 (three different k_msg structures) all ~28us/step, all
// streaming the same 270MB of w2tf L2 reads -> k_msg is L2-broadcast-bound
// (~9.6 TB/s pure-L2). R11 halved the stream but added 3 barriers/iter and
// regressed. R12 halves the stream with ZERO added sync: 128 edges/block,
// 8 waves = (nf-half x kk-group); wave (kg,nfh) owns kk rows kg*16..+15 and
// col-half nfh -> its 4KB/kk staged slice is WAVE-PRIVATE (R10's counted
// vmcnt(4) dbuf discipline unchanged, no loop barriers). hv strips also
// wave-private (dup x2, 32KB). Stream: 528KB per 128 edges = 135MB total.
// Epilogue: 2 nf2-rounds of LDS reduce over 4 kg partials, coalesced stores.
// All other kernels identical to R10.

#define N_NODES 32768
#define N_EDGES 32768
#define STEPS 3

typedef __attribute__((ext_vector_type(8))) short short8;   // 8 bf16 = 4 VGPRs
typedef __attribute__((ext_vector_type(4))) float float4v;  // MFMA C/D

__device__ __forceinline__ float bf2f(unsigned short u) {
    union { unsigned int i; float f; } v; v.i = ((unsigned int)u) << 16; return v.f;
}
__device__ __forceinline__ unsigned short f2bf(float f) {  // RNE
    union { float f; unsigned int i; } v; v.f = f;
    unsigned int x = v.i;
    return (unsigned short)((x + 0x7fffu + ((x >> 16) & 1u)) >> 16);
}

// async global->LDS, 16B/lane; lds dest = wave-uniform base + lane*16
__device__ __forceinline__ void gload_lds16(const void* g, void* l) {
    __builtin_amdgcn_global_load_lds(
        (__attribute__((address_space(1))) void*)g,
        (__attribute__((address_space(3))) void*)l, 16, 0, 0);
}

// ===================== fused setup kernel ==================================
// blockIdx segments:
//  [0,144)       rootTf (4096) + wcombf (32768)      — frag-interleaved
//  [144,1184)    w2tf (266240 valid + 4096 pad)       — frag-interleaved
//  [1184,1232)   wd1f (10240) + wd2f (2048)           — frag-interleaved
//  [1232,9424)   proj: hb = bf16(tanh([x,u]@Wp^T+bp))
//  [9424,17616)  edge hidden TRANSPOSED: hidT[j][e] = relu(ea@We1^T+be1)
//  [17616,17648) zero cnts (32768 floats)
__global__ __launch_bounds__(256) void k_setup(
    const float* __restrict__ root, const float* __restrict__ Wih,
    const float* __restrict__ Whh,
    const float* __restrict__ We2, const float* __restrict__ be2,
    const float* __restrict__ Wd1, const float* __restrict__ bd1,
    const float* __restrict__ Wd2,
    const float* __restrict__ x, const float* __restrict__ u,
    const float* __restrict__ Wp, const float* __restrict__ bp,
    const float* __restrict__ ea, const float* __restrict__ We1,
    const float* __restrict__ be1,
    unsigned short* __restrict__ rootTf, unsigned short* __restrict__ wcombf,
    unsigned short* __restrict__ w2tf,
    unsigned short* __restrict__ wd1f, unsigned short* __restrict__ wd2f,
    unsigned short* __restrict__ hb,
    unsigned short* __restrict__ hidT, float* __restrict__ cnts)
{
    int b = blockIdx.x, tid = threadIdx.x;
    if (b < 144) {
        int i = b * 256 + tid;
        if (i < 4096) {
            int j = i & 7, lane = (i >> 3) & 63, g = i >> 9;   // g<8
            int kb = g >> 2, nf = g & 3;
            int o = nf * 16 + (lane & 15);
            int k = kb * 32 + (lane >> 4) * 8 + j;
            rootTf[i] = f2bf(root[k * 64 + o]);
        } else if (i < 4096 + 32768) {
            int t = i - 4096;
            int j = t & 7, lane = (t >> 3) & 63, g = t >> 9;   // g<64
            int kb = g >> 4, nf = g & 15;
            int cp = nf * 16 + (lane & 15);
            int k = kb * 32 + (lane >> 4) * 8 + j;
            float v;
            if (cp < 128)      v = (k < 64) ? Wih[cp * 64 + k] : Whh[cp * 64 + (k - 64)];
            else if (cp < 192) v = (k < 64) ? Wih[cp * 64 + k] : 0.f;
            else               v = (k < 64) ? 0.f : Whh[(cp - 64) * 64 + (k - 64)];
            wcombf[t] = f2bf(v);
        }
    } else if (b < 1184) {
        int t = (b - 144) * 256 + tid;   // t < 266240
        if (t < 65 * 4096) {
            int kk = t >> 12, r = t & 4095;
            int j = r & 7, lane = (r >> 3) & 63, g = r >> 9;  // g<8
            int half = g >> 2, nf = g & 3;
            int o = nf * 16 + (lane & 15);
            int hh = half * 32 + (lane >> 4) * 8 + j;
            float v = (kk < 64) ? We2[((size_t)(hh * 64 + o)) * 64 + kk]
                                : be2[(size_t)hh * 64 + o];
            w2tf[t] = f2bf(v);
        }
    } else if (b < 1232) {
        int i = (b - 1184) * 256 + tid;
        if (i < 10240) {
            int j = i & 7, lane = (i >> 3) & 63, g = i >> 9;  // g<20
            int kb = g >> 2, nf = g & 3;
            int o = nf * 16 + (lane & 15);
            int k = kb * 32 + (lane >> 4) * 8 + j;
            float v = (k < 133) ? Wd1[(size_t)o * 133 + k] : (k == 133 ? bd1[o] : 0.f);
            wd1f[i] = f2bf(v);
        } else if (i < 10240 + 2048) {
            int t = i - 10240;
            int j = t & 7, lane = (t >> 3) & 63, g = t >> 9;  // g<4
            int kb = g >> 1, nf = g & 1;
            int o = nf * 16 + (lane & 15);
            int k = kb * 32 + (lane >> 4) * 8 + j;
            wd2f[t] = f2bf(Wd2[(size_t)o * 64 + k]);
        }
    } else if (b < 9424) {
        int idx = (b - 1232) * 256 + tid;
        int n = idx >> 6, j = idx & 63;
        const float* wr = Wp + j * 23;
        const float* xr = x + (size_t)n * 12;
        float s = bp[j];
#pragma unroll
        for (int i = 0; i < 12; i++) s += xr[i] * wr[i];
#pragma unroll
        for (int i = 0; i < 11; i++) s += u[i] * wr[12 + i];
        hb[idx] = f2bf(tanhf(s));
    } else if (b < 17616) {
        int idx = (b - 9424) * 256 + tid;           // idx < 2^21
        int el = idx & 63, j = (idx >> 6) & 63, eb = idx >> 12;
        int e = eb * 64 + el;                       // lane-varying e -> coalesced
        float s = be1[j];
#pragma unroll
        for (int i = 0; i < 5; i++) s += ea[(size_t)e * 5 + i] * We1[j * 5 + i];
        hidT[(size_t)j * N_EDGES + e] = f2bf(s > 0.f ? s : 0.f);
    } else {
        int idx = (b - 17616) * 1024 + tid * 4;
        if (idx < 32768) {
            float4v z = {0.f, 0.f, 0.f, 0.f};
            *(float4v*)(cnts + idx) = z;
        }
    }
}

__global__ __launch_bounds__(256) void k_counts(
    const int* __restrict__ ei, float* __restrict__ counts)
{
    int i = blockIdx.x * 256 + threadIdx.x;
    if (i < N_EDGES) atomicAdd(&counts[ei[N_EDGES + i]], 1.0f);
}

// one-time exclusive prefix sum of counts -> off[0..N], plus working copy woff
__global__ __launch_bounds__(1024) void k_scan(
    const float* __restrict__ cnts, int* __restrict__ off, int* __restrict__ woff)
{
    __shared__ int part[1024];
    int t = threadIdx.x;
    int loc[32];
    int s = 0;
#pragma unroll
    for (int i = 0; i < 32; i++) { loc[i] = s; s += (int)cnts[t * 32 + i]; }
    part[t] = s;
    __syncthreads();
    for (int d = 1; d < 1024; d <<= 1) {
        int y = (t >= d) ? part[t - d] : 0;
        __syncthreads();
        part[t] += y;
        __syncthreads();
    }
    int pre = (t == 0) ? 0 : part[t - 1];
#pragma unroll
    for (int i = 0; i < 32; i++) {
        off[t * 32 + i] = pre + loc[i];
        woff[t * 32 + i] = pre + loc[i];
    }
    if (t == 1023) off[32768] = part[1023];
}

// one-time: place edge ids into dst-sorted slots (32K atomics, once)
__global__ __launch_bounds__(256) void k_scatter(
    const int* __restrict__ ei, int* __restrict__ woff, int* __restrict__ eorder)
{
    int e = blockIdx.x * 256 + threadIdx.x;
    if (e < N_EDGES) {
        int d = ei[N_EDGES + e];
        int slot = atomicAdd(&woff[d], 1);
        eorder[slot] = e;
    }
}

// ===================== fused msg GEMM ======================================
// 256 blocks x 512 threads = 8 waves: wave = nfh*4 + kg.
// kg in {0..3}: kk-slice kg*16..+15 (kg=3 also kk=64 bias row).
// nfh in {0,1}: output col-half (nf in {nfh*2, nfh*2+1}).
// Each wave's staged slice (4KB per kk-row: 4 frag-groups) is WAVE-PRIVATE,
// double-buffered; counted vmcnt(4); NO barriers in the loop (R10 discipline).
// Per-block w2tf stream = 528KB for 128 edges -> total 135MB (half of R10).
// hv strips wave-private (16 rows x 128 e, dup x2 across nfh; no barrier).
// Epilogue: 2 nf2-rounds of LDS reduce over the 4 kg partials.
__global__ __launch_bounds__(512, 2) void k_msg_fused(
    const unsigned short* __restrict__ hidT,  // (64, E) bf16
    const unsigned short* __restrict__ hb,    // (N,64) bf16
    const unsigned short* __restrict__ w2tf,  // (66*4096) frag-interleaved
    const int* __restrict__ ei,
    float* __restrict__ msgbuf)               // (E,64) f32 dense
{
    // LDS: [0,65536)      stage: 8 waves x 2 db x 2048 ushort (4KB slices)
    //      [65536,98304)  hvp: 8 waves x 16 rows x 128 e bf16 (wave-private)
    //      reduce overlay on stage: red[4 kg][128 row][34] f32 = 69632B
    __shared__ __attribute__((aligned(16))) unsigned char smem[98304];
    unsigned short* stg = (unsigned short*)smem;
    unsigned short* hvl = (unsigned short*)(smem + 65536);
    float* red = (float*)smem;

    int tid = threadIdx.x, w = tid >> 6, lane = tid & 63;
    int l15 = lane & 15, quad = lane >> 4;
    int kg = w & 3, nfh = w >> 2;
    int ebase = blockIdx.x * 128;
    int n_w = 16 + (kg == 3 ? 1 : 0);   // kg3 takes the bias row kk=64

    unsigned short* hvp = hvl + w * 2048;    // my 16 rows x 128 edges
    // ---- preamble: my kk-slice's hv rows -> wave-private LDS strip ----
#pragma unroll
    for (int r2 = 0; r2 < 16; r2++) {
        unsigned int v = *((const unsigned int*)(hidT + (size_t)(kg * 16 + r2) * N_EDGES + ebase) + lane);
        *((unsigned int*)hvp + r2 * 64 + lane) = v;
    }
    // ---- static A-frags: 8 edge-tiles x 2 K-halves of h[src] (bf16) ----
    short8 afr[8][2];
#pragma unroll
    for (int t = 0; t < 8; t++) {
        int src = ei[ebase + t * 16 + l15];
#pragma unroll
        for (int hh = 0; hh < 2; hh++)
            afr[t][hh] = *(const short8*)(hb + (size_t)src * 64 + hh * 32 + quad * 8);
    }

    unsigned short* wbuf = stg + w * 4096;   // 2 db x 2048
    // stage kk-row (kg*16+r)'s 4 frag-groups for my nf-half into wbuf[db]
    auto stage = [&](int r, int db) {
        const unsigned short* g = w2tf + (size_t)(kg * 16 + r) * 4096;
        unsigned short* d = wbuf + db * 2048;
#pragma unroll
        for (int c = 0; c < 4; c++) {             // c = hh*2 + j (j = nf2)
            int hh = c >> 1, j = c & 1;
            gload_lds16(g + (hh * 4 + nfh * 2 + j) * 512 + lane * 8, d + c * 512);
        }
    };

    stage(0, 0);
    stage(1, 1);
    asm volatile("s_waitcnt lgkmcnt(0)" ::: "memory");  // my hvp ds_writes done

    float4v acc[8][2] = {};   // [tile][nf2]
    for (int r = 0; r < n_w; r++) {
        int db = r & 1;
        // stage r complete; stage r+1's 4 loads may remain in flight
        if (r < n_w - 1) { asm volatile("s_waitcnt vmcnt(4)" ::: "memory"); }
        else             { asm volatile("s_waitcnt vmcnt(0)" ::: "memory"); }

        bool bias = (r == 16);
        short8 bfr[2][2];
        const unsigned short* bb = wbuf + db * 2048;
#pragma unroll
        for (int hh = 0; hh < 2; hh++)
#pragma unroll
            for (int j = 0; j < 2; j++)
                bfr[hh][j] = *(const short8*)(bb + (hh * 2 + j) * 512 + lane * 8);

        unsigned long long hu[8] = {};
        if (!bias) {
#pragma unroll
            for (int t = 0; t < 8; t++)
                hu[t] = *(const unsigned long long*)(hvp + r * 128 + t * 16 + quad * 4);
        }

        asm volatile("s_waitcnt lgkmcnt(0)" ::: "memory");  // my LDS reads done
        if (r + 2 < n_w) stage(r + 2, db);

#pragma unroll
        for (int t = 0; t < 8; t++) {
            float4v z = {0.f, 0.f, 0.f, 0.f};
            float4v T0 = __builtin_amdgcn_mfma_f32_16x16x32_bf16(afr[t][0], bfr[0][0], z, 0, 0, 0);
            T0 = __builtin_amdgcn_mfma_f32_16x16x32_bf16(afr[t][1], bfr[1][0], T0, 0, 0, 0);
            float4v T1 = __builtin_amdgcn_mfma_f32_16x16x32_bf16(afr[t][0], bfr[0][1], z, 0, 0, 0);
            T1 = __builtin_amdgcn_mfma_f32_16x16x32_bf16(afr[t][1], bfr[1][1], T1, 0, 0, 0);
#pragma unroll
            for (int rr = 0; rr < 4; rr++) {
                float hvv = bias ? 1.0f : bf2f((unsigned short)(hu[t] >> (16 * rr)));
                acc[t][0][rr] += hvv * T0[rr];
                acc[t][1][rr] += hvv * T1[rr];
            }
        }
    }

    // ---- reduce 4 kg partials in 2 nf2-rounds (red overlays stage) ----
    int row_r = tid >> 2, cq = tid & 3;        // 128 rows x 4 col-chunks of 8
#pragma unroll
    for (int nf2 = 0; nf2 < 2; nf2++) {
        __syncthreads();   // red region free (round 0: also closes main loop)
#pragma unroll
        for (int t = 0; t < 8; t++)
#pragma unroll
            for (int rr = 0; rr < 4; rr++)
                red[kg * 4352 + (t * 16 + quad * 4 + rr) * 34 + nfh * 16 + l15] = acc[t][nf2][rr];
        __syncthreads();
        // thread sums cols c34 = cq*8..+8 over 4 kg; c34>>4 = nfh, nf = nfh*2+nf2
        float s[8];
#pragma unroll
        for (int i = 0; i < 8; i++) s[i] = 0.f;
#pragma unroll
        for (int g2 = 0; g2 < 4; g2++) {
            const float* rp = red + g2 * 4352 + row_r * 34 + cq * 8;
#pragma unroll
            for (int i = 0; i < 8; i++) s[i] += rp[i];
        }
        int c34 = cq * 8;
        int gcol = ((c34 >> 4) * 2 + nf2) * 16 + (c34 & 15);
        float* op = msgbuf + (size_t)(ebase + row_r) * 64 + gcol;
        float4v v0 = { s[0], s[1], s[2], s[3] };
        float4v v1 = { s[4], s[5], s[6], s[7] };
        *(float4v*)(op) = v0;
        *(float4v*)(op + 4) = v1;
    }
}

// ===================== fused node update ===================================
// Gathers msgbuf rows via dst-sorted edge list (no atomics, no agg buffer).
__global__ __launch_bounds__(256) void k_node(
    const unsigned short* __restrict__ hb_in,
    const unsigned short* __restrict__ rootTf,
    const unsigned short* __restrict__ wcombf,
    const float* __restrict__ msgbuf, const int* __restrict__ off,
    const int* __restrict__ eorder,
    const float* __restrict__ counts,
    const float* __restrict__ conv_b,
    const float* __restrict__ bih, const float* __restrict__ bhh,
    unsigned short* __restrict__ hb_out)
{
    __shared__ unsigned short m_lds[64 * 72];
    __shared__ float aggl[64 * 68];
    int tid = threadIdx.x, w = tid >> 6, lane = tid & 63;
    int l15 = lane & 15, quad = lane >> 4;
    int node0 = blockIdx.x * 64;
    int row0 = w * 16;

    // ---- gather-aggregate: 4 threads per node x 16 cols ----
    {
        int nl = tid >> 2, cg = tid & 3;
        int nn = node0 + nl;
        int s0 = off[nn], s1 = off[nn + 1];
        float acc[16] = {};
        for (int sl = s0; sl < s1; sl++) {
            int e = eorder[sl];
            const float* mr = msgbuf + (size_t)e * 64 + cg * 16;
#pragma unroll
            for (int q = 0; q < 4; q++) {
                float4v v = *(const float4v*)(mr + 4 * q);
#pragma unroll
                for (int j = 0; j < 4; j++) acc[4 * q + j] += v[j];
            }
        }
#pragma unroll
        for (int k = 0; k < 16; k++) aggl[nl * 68 + cg * 16 + k] = acc[k];
    }
    __syncthreads();

    float4v acc1[4] = {};
    {
        short8 a1[2];
#pragma unroll
        for (int kb = 0; kb < 2; kb++)
            a1[kb] = *(const short8*)(hb_in + (size_t)(node0 + row0 + l15) * 64 + kb * 32 + quad * 8);
#pragma unroll
        for (int kb = 0; kb < 2; kb++)
#pragma unroll
            for (int nf = 0; nf < 4; nf++) {
                short8 b = *(const short8*)(rootTf + (size_t)((kb * 4 + nf) * 64 + lane) * 8);
                acc1[nf] = __builtin_amdgcn_mfma_f32_16x16x32_bf16(a1[kb], b, acc1[nf], 0, 0, 0);
            }
    }
#pragma unroll
    for (int rr = 0; rr < 4; rr++) {
        int nl = row0 + quad * 4 + rr;
        float cnt = counts[node0 + nl]; if (cnt < 1.f) cnt = 1.f;
        float rcp = 1.f / cnt;
#pragma unroll
        for (int nf = 0; nf < 4; nf++) {
            int c = nf * 16 + l15;
            float av = aggl[nl * 68 + c];
            float mv = av * rcp + acc1[nf][rr] + conv_b[c];
            m_lds[nl * 72 + c] = f2bf(mv > 0.f ? mv : 0.f);
        }
    }
    __syncthreads();

    float4v acc2[16] = {};
#pragma unroll
    for (int kb = 0; kb < 4; kb++) {
        short8 a2;
        if (kb < 2)
            a2 = *(const short8*)(m_lds + (row0 + l15) * 72 + kb * 32 + quad * 8);
        else
            a2 = *(const short8*)(hb_in + (size_t)(node0 + row0 + l15) * 64 + (kb - 2) * 32 + quad * 8);
#pragma unroll
        for (int nf = 0; nf < 16; nf++) {
            short8 b = *(const short8*)(wcombf + (size_t)((kb * 16 + nf) * 64 + lane) * 8);
            acc2[nf] = __builtin_amdgcn_mfma_f32_16x16x32_bf16(a2, b, acc2[nf], 0, 0, 0);
        }
    }

#pragma unroll
    for (int nf0 = 0; nf0 < 4; nf0++) {
        int c = nf0 * 16 + l15;
        float br = bih[c] + bhh[c];
        float bz = bih[64 + c] + bhh[64 + c];
        float bni = bih[128 + c], bnh = bhh[128 + c];
#pragma unroll
        for (int rr = 0; rr < 4; rr++) {
            int node = node0 + row0 + quad * 4 + rr;
            float gr = 1.f / (1.f + __expf(-(acc2[nf0][rr] + br)));
            float gz = 1.f / (1.f + __expf(-(acc2[nf0 + 4][rr] + bz)));
            float ng = tanhf(acc2[nf0 + 8][rr] + bni + gr * (acc2[nf0 + 12][rr] + bnh));
            float ho = bf2f(hb_in[(size_t)node * 64 + c]);
            float hn = (1.f - gz) * ng + gz * ho;
            hb_out[(size_t)node * 64 + c] = f2bf(hn);
        }
    }
}

// ===================== MFMA decoder ========================================
__global__ __launch_bounds__(256) void k_decoder(
    const unsigned short* __restrict__ hb, const int* __restrict__ ei,
    const float* __restrict__ ea,
    const unsigned short* __restrict__ wd1f, const unsigned short* __restrict__ wd2f,
    const float* __restrict__ bd2,
    const float* __restrict__ Wd3, const float* __restrict__ bd3,
    float* __restrict__ out)
{
    __shared__ unsigned short d1f[4][1024];  // per-wave: 2 frags x 512
    __shared__ float d2s[4][16 * 33];        // per-wave: 16 edges x 32 (+pad)
    int tid = threadIdx.x, w = tid >> 6, lane = tid & 63;
    int l15 = lane & 15, quad = lane >> 4;
    int ebase = blockIdx.x * 64 + w * 16;
    int e = ebase + l15;
    int src = ei[e], dst = ei[N_EDGES + e];

    short8 a[5];
#pragma unroll
    for (int kb = 0; kb < 2; kb++) {
        a[kb]     = *(const short8*)(hb + (size_t)src * 64 + kb * 32 + quad * 8);
        a[2 + kb] = *(const short8*)(hb + (size_t)dst * 64 + kb * 32 + quad * 8);
    }
    {
        union { short8 v; unsigned short u[8]; } tea;
#pragma unroll
        for (int j = 0; j < 8; j++) {
            float vv = 0.f;
            if (quad == 0) vv = (j < 5) ? ea[(size_t)e * 5 + j] : (j == 5 ? 1.f : 0.f);
            tea.u[j] = f2bf(vv);
        }
        a[4] = tea.v;
    }

    float4v acc1[4] = {};
#pragma unroll
    for (int kb = 0; kb < 5; kb++)
#pragma unroll
        for (int nf = 0; nf < 4; nf++) {
            short8 b = *(const short8*)(wd1f + (size_t)((kb * 4 + nf) * 64 + lane) * 8);
            acc1[nf] = __builtin_amdgcn_mfma_f32_16x16x32_bf16(a[kb], b, acc1[nf], 0, 0, 0);
        }
#pragma unroll
    for (int nf = 0; nf < 4; nf++) {
        int kbp = nf >> 1;
        int lanep_hi = ((nf & 1) * 2 + (l15 >> 3)) * 16;
        int jp = l15 & 7;
#pragma unroll
        for (int r = 0; r < 4; r++) {
            float v = acc1[nf][r];
            d1f[w][kbp * 512 + (lanep_hi + quad * 4 + r) * 8 + jp] = f2bf(v > 0.f ? v : 0.f);
        }
    }
    float4v acc2[2] = {};
#pragma unroll
    for (int kb = 0; kb < 2; kb++) {
        short8 a2 = *(const short8*)(&d1f[w][kb * 512 + lane * 8]);
#pragma unroll
        for (int nf = 0; nf < 2; nf++) {
            short8 b = *(const short8*)(wd2f + (size_t)((kb * 2 + nf) * 64 + lane) * 8);
            acc2[nf] = __builtin_amdgcn_mfma_f32_16x16x32_bf16(a2, b, acc2[nf], 0, 0, 0);
        }
    }
#pragma unroll
    for (int nf = 0; nf < 2; nf++) {
        int c = nf * 16 + l15;
        float bias = bd2[c];
#pragma unroll
        for (int r = 0; r < 4; r++) {
            float v = acc2[nf][r] + bias;
            d2s[w][(quad * 4 + r) * 33 + c] = v > 0.f ? v : 0.f;
        }
    }
    {
        int e_l = lane >> 2, t = lane & 3;
        float s = bd3[t];
        const float* w3 = Wd3 + t * 32;
        const float* dr = &d2s[w][e_l * 33];
#pragma unroll
        for (int k = 0; k < 32; k++) s += w3[k] * dr[k];
        out[(size_t)(ebase + e_l) * 4 + t] = s;
    }
}

extern "C" void kernel_launch(void* const* d_in, const int* in_sizes, int n_in,
                              void* d_out, int out_size, void* d_ws, size_t ws_size,
                              hipStream_t stream)
{
    const float* x      = (const float*)d_in[0];
    const int*   ei     = (const int*)d_in[1];
    const float* ea     = (const float*)d_in[2];
    const float* u      = (const float*)d_in[3];
    const float* Wp     = (const float*)d_in[4];
    const float* bp     = (const float*)d_in[5];
    const float* We1    = (const float*)d_in[6];
    const float* be1    = (const float*)d_in[7];
    const float* We2    = (const float*)d_in[8];
    const float* be2    = (const float*)d_in[9];
    const float* root   = (const float*)d_in[10];
    const float* conv_b = (const float*)d_in[11];
    const float* Wih    = (const float*)d_in[12];
    const float* bih    = (const float*)d_in[13];
    const float* Whh    = (const float*)d_in[14];
    const float* bhh    = (const float*)d_in[15];
    const float* Wd1    = (const float*)d_in[16];
    const float* bd1    = (const float*)d_in[17];
    const float* Wd2    = (const float*)d_in[18];
    const float* bd2    = (const float*)d_in[19];
    const float* Wd3    = (const float*)d_in[20];
    const float* bd3    = (const float*)d_in[21];
    float* out = (float*)d_out;

    char* ws = (char*)d_ws;
    size_t off_b = 0;
    auto take = [&](size_t bytes) -> char* {
        char* p = ws + off_b; off_b = (off_b + bytes + 255) & ~(size_t)255; return p;
    };
    unsigned short* hb     = (unsigned short*)take((size_t)N_NODES * 64 * 2);
    unsigned short* hidT   = (unsigned short*)take((size_t)N_EDGES * 64 * 2);
    float*          msgbuf = (float*)take((size_t)N_EDGES * 64 * 4);
    float*          cnts   = (float*)take((size_t)N_NODES * 4);
    int*            off    = (int*)take((size_t)(N_NODES + 1) * 4);
    int*            woff   = (int*)take((size_t)N_NODES * 4);
    int*            eorder = (int*)take((size_t)N_EDGES * 4);
    unsigned short* w2tf   = (unsigned short*)take((size_t)66 * 4096 * 2);  // +1 pad blk
    unsigned short* rootTf = (unsigned short*)take((size_t)4096 * 2);
    unsigned short* wcombf = (unsigned short*)take((size_t)32768 * 2);
    unsigned short* wd1f   = (unsigned short*)take((size_t)10240 * 2);
    unsigned short* wd2f   = (unsigned short*)take((size_t)2048 * 2);
    (void)ws_size;

    k_setup<<<17648, 256, 0, stream>>>(root, Wih, Whh, We2, be2, Wd1, bd1, Wd2,
                                       x, u, Wp, bp, ea, We1, be1,
                                       rootTf, wcombf, w2tf, wd1f, wd2f,
                                       hb, hidT, cnts);
    k_counts<<<128, 256, 0, stream>>>(ei, cnts);
    k_scan<<<1, 1024, 0, stream>>>(cnts, off, woff);
    k_scatter<<<128, 256, 0, stream>>>(ei, woff, eorder);

    for (int s = 0; s < STEPS; s++) {
        k_msg_fused<<<N_EDGES / 128, 512, 0, stream>>>(hidT, hb, w2tf, ei, msgbuf);
        k_node<<<N_NODES / 64, 256, 0, stream>>>(hb, rootTf, wcombf, msgbuf, off,
                                                 eorder, cnts, conv_b, bih, bhh, hb);
    }
    k_decoder<<<N_EDGES / 64, 256, 0, stream>>>(hb, ei, ea, wd1f, wd2f, bd2,
                                                Wd3, bd3, out);
}